// Round 8
// baseline (303.758 us; speedup 1.0000x reference)
//
#include <hip/hip_runtime.h>
#include <hip/hip_fp16.h>
#include <stdint.h>

// Problem constants
#define BB 2
#define HH 16
#define SS 2048
#define DD 1024
#define DHH 64
// SCALE * log2(e): logits computed directly in log2 domain
#define QSCALE 0.18033688011112042f

typedef _Float16 half8 __attribute__((ext_vector_type(8)));
typedef _Float16 half4 __attribute__((ext_vector_type(4)));
typedef __fp16 fp16x2 __attribute__((ext_vector_type(2)));
typedef float floatx4 __attribute__((ext_vector_type(4)));

__device__ __forceinline__ floatx4 mfma16(half8 a, half8 b, floatx4 c) {
  return __builtin_amdgcn_mfma_f32_16x16x32_f16(a, b, c, 0, 0, 0);
}

// Async global->LDS DMA, 16B per lane (1KB per wave-issue).  LDS dest is
// wave-uniform base + lane*16 (m97 recipe).
__device__ __forceinline__ void dma16(const _Float16* g, _Float16* l) {
  __builtin_amdgcn_global_load_lds(
      (const __attribute__((address_space(1))) uint32_t*)g,
      (__attribute__((address_space(3))) uint32_t*)l,
      16, 0, 0);
}

// Tile layout for DMA-staged [128 rows][32 cols f16] (row = 64B = 4 chunks of
// 16B).  XOR swizzle within a 128B row-pair (8 chunks): global (row, chunk c)
// lives at LDS chunk ((row&1)*4 + c) ^ ((row>>1)&7) of row-pair row>>1.
// DMA side: lane i of an issue covering rows [R,R+16) writes LDS linear chunk
// i, which must hold global g = (i&7)^((i>>3)&7): row R+(i>>3)*2+(g>>2),
// col-chunk g&3.  Read side: lanes map 2-per-chunk-group -> conflict-free.

// ---------------------------------------------------------------------------
// Kernel 0a: weight conversion (once per call).
//  z<3 : w_z[h] fp32 [1024 k][64 e]  -> Wh/Wl f16 [n=z*1024+h*64+e][1024 k]
//  z==3: wo flat fp32 [1024 k][1024 d] -> Wot f16 [n=d][1024 k]   (single f16)
// ---------------------------------------------------------------------------
__global__ __launch_bounds__(256) void convert_kernel(
    const float* __restrict__ wq, const float* __restrict__ wk,
    const float* __restrict__ wv, const float* __restrict__ wo,
    _Float16* __restrict__ Wh, _Float16* __restrict__ Wl,
    _Float16* __restrict__ Wot)
{
  __shared__ float St[64][68];
  const int kt = blockIdx.x;       // k-tile (64 rows)
  const int hy = blockIdx.y;       // h (z<3) or d-tile (z==3)
  const int z  = blockIdx.z;
  const int t  = (int)threadIdx.x;
  const int k0 = kt * 64;

  const float* src = (z == 0) ? (wq + hy * (DD * DHH))
                   : (z == 1) ? (wk + hy * (DD * DHH))
                   : (z == 2) ? (wv + hy * (DD * DHH))
                   : wo;

  const int rr = t >> 4, cc = (t & 15) * 4;
  if (z < 3) {
    #pragma unroll
    for (int i = 0; i < 4; ++i)
      *(floatx4*)&St[rr + 16 * i][cc] =
          *(const floatx4*)(src + (k0 + rr + 16 * i) * DHH + cc);
  } else {
    const int d0 = hy * 64;
    #pragma unroll
    for (int i = 0; i < 4; ++i)
      *(floatx4*)&St[rr + 16 * i][cc] =
          *(const floatx4*)(src + (k0 + rr + 16 * i) * 1024 + d0 + cc);
  }
  __syncthreads();

  const int e = t >> 2, kc = (t & 3) * 16;
  if (z < 3) {
    const int n = z * 1024 + hy * 64 + e;
    half8 hi0, hi1, lo0, lo1;
    #pragma unroll
    for (int u = 0; u < 16; ++u) {
      float x = St[kc + u][e];
      _Float16 hh = (_Float16)x;
      _Float16 ll = (_Float16)(x - (float)hh);
      if (u < 8) { hi0[u] = hh; lo0[u] = ll; }
      else       { hi1[u - 8] = hh; lo1[u - 8] = ll; }
    }
    *(half8*)(Wh + n * 1024 + k0 + kc)     = hi0;
    *(half8*)(Wh + n * 1024 + k0 + kc + 8) = hi1;
    *(half8*)(Wl + n * 1024 + k0 + kc)     = lo0;
    *(half8*)(Wl + n * 1024 + k0 + kc + 8) = lo1;
  } else {
    const int d0 = hy * 64;
    half8 hi0, hi1;
    #pragma unroll
    for (int u = 0; u < 16; ++u) {
      _Float16 hh = (_Float16)St[kc + u][e];
      if (u < 8) hi0[u] = hh; else hi1[u - 8] = hh;
    }
    *(half8*)(Wot + (d0 + e) * 1024 + k0 + kc)     = hi0;
    *(half8*)(Wot + (d0 + e) * 1024 + k0 + kc + 8) = hi1;
  }
}

// ---------------------------------------------------------------------------
// Kernel 0b: token split (elementwise, memory-bound).
// ---------------------------------------------------------------------------
__global__ __launch_bounds__(256) void tokens_split_kernel(
    const float* __restrict__ tokens,
    _Float16* __restrict__ th, _Float16* __restrict__ tl)
{
  const int i = ((int)blockIdx.x * 256 + (int)threadIdx.x) * 8;
  floatx4 x0 = *(const floatx4*)(tokens + i);
  floatx4 x1 = *(const floatx4*)(tokens + i + 4);
  half8 h, l;
  #pragma unroll
  for (int j = 0; j < 8; ++j) {
    float x = (j < 4) ? x0[j] : x1[j - 4];
    _Float16 hh = (_Float16)x;
    h[j] = hh;
    l[j] = (_Float16)(x - (float)hh);
  }
  *(half8*)(th + i) = h;
  *(half8*)(tl + i) = l;
}

// ---------------------------------------------------------------------------
// Kernel 1: fused QKV GEMM.  C[4096 m][3072 n], 128x128 tiles.
// m97-style staging: global_load_lds width=16, one array per wave
// (w0:Ah w1:Bh w2:Bl w3:Al), XOR-swizzled unpadded tiles.  No staging VGPRs.
// Blocks bx 0..7: q (split-3), 8..15: k (split-3), 16..23: v (split-2).
// ---------------------------------------------------------------------------
__global__ __launch_bounds__(256) void qkv_gemm_kernel(
    const _Float16* __restrict__ th, const _Float16* __restrict__ tl,
    const _Float16* __restrict__ Wh, const _Float16* __restrict__ Wl,
    _Float16* __restrict__ qh, _Float16* __restrict__ ql,
    _Float16* __restrict__ kh, _Float16* __restrict__ kl,
    _Float16* __restrict__ vt)
{
  __shared__ alignas(16) _Float16 sAh[128 * 32];
  __shared__ alignas(16) _Float16 sAl[128 * 32];
  __shared__ alignas(16) _Float16 sBh[128 * 32];
  __shared__ alignas(16) _Float16 sBl[128 * 32];

  const int n0 = blockIdx.x * 128;   // 0..23
  const int m0 = blockIdx.y * 128;   // 0..31
  const int zb = n0 >> 10;           // 0=q, 1=k, 2=v (uniform per block)
  const bool is_v = (zb == 2);
  const int t = (int)threadIdx.x;
  const int lane = t & 63, wid = t >> 6;
  const int l16 = lane & 15, q4 = lane >> 4;
  const int mw = (wid & 1) * 64, nw = (wid >> 1) * 64;

  // DMA lane mapping (per 16-row issue)
  const int g  = (lane & 7) ^ ((lane >> 3) & 7);
  const int grow  = (lane >> 3) * 2 + (g >> 2);  // row within issue
  const int gcol8 = (g & 3) * 8;                 // col (halfs)

  // fragment-read lane offset (bytes within a tile)
  const int laneoff = (l16 >> 1) * 128 + (((((l16 & 1) << 2) | q4) ^ (l16 >> 1)) * 16);

  // this wave's staging assignment
  const _Float16* src;
  _Float16* dst;
  if (wid == 0)      { src = th + m0 * 1024; dst = sAh; }
  else if (wid == 1) { src = Wh + n0 * 1024; dst = sBh; }
  else if (wid == 2) { src = Wl + n0 * 1024; dst = sBl; }
  else               { src = tl + m0 * 1024; dst = sAl; }
  const bool stage_active = !(is_v && wid == 3);
  const _Float16* gsrc = src + grow * 1024 + gcol8;

  const floatx4 z4 = {0.0f, 0.0f, 0.0f, 0.0f};
  floatx4 acc[4][4];
  #pragma unroll
  for (int mi = 0; mi < 4; ++mi)
    #pragma unroll
    for (int ni = 0; ni < 4; ++ni) acc[mi][ni] = z4;

  for (int kt = 0; kt < 32; ++kt) {
    __syncthreads();               // all waves done reading previous tile
    if (stage_active) {
      const _Float16* gp = gsrc + kt * 32;
      #pragma unroll
      for (int j = 0; j < 8; ++j)
        dma16(gp + j * 16 * 1024, dst + j * 16 * 32);
    }
    __syncthreads();               // DMA drained (vmcnt(0) before barrier)

    half8 a_h[4];
    #pragma unroll
    for (int mi = 0; mi < 4; ++mi)
      a_h[mi] = *(const half8*)((const char*)sAh + (mw + mi * 16) * 64 + laneoff);
    if (!is_v) {
      half8 a_l[4];
      #pragma unroll
      for (int mi = 0; mi < 4; ++mi)
        a_l[mi] = *(const half8*)((const char*)sAl + (mw + mi * 16) * 64 + laneoff);
      #pragma unroll
      for (int ni = 0; ni < 4; ++ni) {
        const half8 b_h = *(const half8*)((const char*)sBh + (nw + ni * 16) * 64 + laneoff);
        const half8 b_l = *(const half8*)((const char*)sBl + (nw + ni * 16) * 64 + laneoff);
        #pragma unroll
        for (int mi = 0; mi < 4; ++mi) {
          acc[mi][ni] = mfma16(a_h[mi], b_h, acc[mi][ni]);
          acc[mi][ni] = mfma16(a_h[mi], b_l, acc[mi][ni]);
          acc[mi][ni] = mfma16(a_l[mi], b_h, acc[mi][ni]);
        }
      }
    } else {
      #pragma unroll
      for (int ni = 0; ni < 4; ++ni) {
        const half8 b_h = *(const half8*)((const char*)sBh + (nw + ni * 16) * 64 + laneoff);
        const half8 b_l = *(const half8*)((const char*)sBl + (nw + ni * 16) * 64 + laneoff);
        #pragma unroll
        for (int mi = 0; mi < 4; ++mi) {
          acc[mi][ni] = mfma16(a_h[mi], b_h, acc[mi][ni]);
          acc[mi][ni] = mfma16(a_h[mi], b_l, acc[mi][ni]);
        }
      }
    }
  }

  // epilogue: C row=(q4*4+r within 16-tile), col=l16; zb uniform
  #pragma unroll
  for (int ni = 0; ni < 4; ++ni) {
    const int ncol = n0 + nw + ni * 16;
    const int h = (ncol >> 6) & 15;
    const int e = (ncol & 63) + l16;
    #pragma unroll
    for (int mi = 0; mi < 4; ++mi) {
      #pragma unroll
      for (int r = 0; r < 4; ++r) {
        const int grow2 = m0 + mw + mi * 16 + q4 * 4 + r;
        const int b = grow2 >> 11, s = grow2 & 2047;
        const float v = acc[mi][ni][r];
        const int qkidx = ((b * HH + h) * SS + s) * DHH + e;
        if (zb == 0) {
          const float vs = v * QSCALE;
          const _Float16 hh = (_Float16)vs;
          qh[qkidx] = hh;
          ql[qkidx] = (_Float16)(vs - (float)hh);
        } else if (zb == 1) {
          const _Float16 hh = (_Float16)v;
          kh[qkidx] = hh;
          kl[qkidx] = (_Float16)(v - (float)hh);
        } else {
          vt[((b * HH + h) * DHH + e) * SS + s] = (_Float16)v;
        }
      }
    }
  }
}

// ---------------------------------------------------------------------------
// Kernel 2: flash attention, transposed orientation, 512-thread blocks.
// Block = (b, h, 128-query tile), 8 waves; query index on the lane axis.
//   S^T = mfma(A=K-frag, B=Q-frag);  agg^T = mfma(A=V^T-frag, B=P-frag)
// (unchanged from R7 — passed at <103 us)
// ---------------------------------------------------------------------------
__global__ __launch_bounds__(512) void attn_kernel(
    const _Float16* __restrict__ qh, const _Float16* __restrict__ ql,
    const _Float16* __restrict__ kh, const _Float16* __restrict__ kl,
    const _Float16* __restrict__ vt, _Float16* __restrict__ agg)
{
  __shared__ _Float16 Kh[64][72], Kl[64][72], Vs[64][72];
  __shared__ _Float16 Ps[128][72];   // [query][key], wave-private 16-row bands

  const int qt = blockIdx.x;   // 0..15 (128 queries)
  const int h  = blockIdx.y;   // 0..15
  const int b  = blockIdx.z;   // 0..1
  const int bh = b * HH + h;
  const int t = (int)threadIdx.x;
  const int lane = t & 63, wid = t >> 6;   // wid 0..7
  const int l16 = lane & 15, q4 = lane >> 4;

  const int sr = t >> 3, sc = (t & 7) * 8;

  half8 qfh[2], qfl[2];
  {
    const int s = qt * 128 + wid * 16 + l16;
    const int base = (bh * SS + s) * DHH + q4 * 8;
    qfh[0] = *(const half8*)(qh + base);
    qfh[1] = *(const half8*)(qh + base + 32);
    qfl[0] = *(const half8*)(ql + base);
    qfl[1] = *(const half8*)(ql + base + 32);
  }

  const floatx4 z4 = {0.0f, 0.0f, 0.0f, 0.0f};
  floatx4 o[4];
  #pragma unroll
  for (int i = 0; i < 4; ++i) o[i] = z4;
  float m_r = -1e30f, l_r = 0.0f;

  half8 pK, pL, pV;
  {
    const int gk = (bh * SS + sr) * DHH + sc;
    pK = *(const half8*)(kh + gk);
    pL = *(const half8*)(kl + gk);
    pV = *(const half8*)(vt + (bh * DHH + sr) * SS + sc);
  }

  for (int kt = 0; kt < 32; ++kt) {
    __syncthreads();
    *(half8*)&Kh[sr][sc] = pK;
    *(half8*)&Kl[sr][sc] = pL;
    *(half8*)&Vs[sr][sc] = pV;
    __syncthreads();

    if (kt < 31) {
      const int k1 = (kt + 1) * 64;
      const int gk = (bh * SS + k1 + sr) * DHH + sc;
      pK = *(const half8*)(kh + gk);
      pL = *(const half8*)(kl + gk);
      pV = *(const half8*)(vt + (bh * DHH + sr) * SS + k1 + sc);
    }

    floatx4 sv[4];
    #pragma unroll
    for (int sub = 0; sub < 4; ++sub) {
      const half8 ah0 = *(const half8*)&Kh[sub * 16 + l16][q4 * 8];
      const half8 ah1 = *(const half8*)&Kh[sub * 16 + l16][q4 * 8 + 32];
      const half8 al0 = *(const half8*)&Kl[sub * 16 + l16][q4 * 8];
      const half8 al1 = *(const half8*)&Kl[sub * 16 + l16][q4 * 8 + 32];
      floatx4 s4 = z4;
      s4 = mfma16(ah0, qfh[0], s4);
      s4 = mfma16(ah1, qfh[1], s4);
      s4 = mfma16(al0, qfh[0], s4);
      s4 = mfma16(al1, qfh[1], s4);
      s4 = mfma16(ah0, qfl[0], s4);
      s4 = mfma16(ah1, qfl[1], s4);
      sv[sub] = s4;
    }

    float mx = fmaxf(fmaxf(sv[0][0], sv[0][1]), fmaxf(sv[0][2], sv[0][3]));
    #pragma unroll
    for (int sub = 1; sub < 4; ++sub)
      mx = fmaxf(mx, fmaxf(fmaxf(sv[sub][0], sv[sub][1]),
                           fmaxf(sv[sub][2], sv[sub][3])));
    mx = fmaxf(mx, __shfl_xor(mx, 16));
    mx = fmaxf(mx, __shfl_xor(mx, 32));
    const float mnew = fmaxf(m_r, mx);

    float psum = 0.0f;
    #pragma unroll
    for (int sub = 0; sub < 4; ++sub) {
      #pragma unroll
      for (int r = 0; r < 4; ++r) {
        float p = exp2f(sv[sub][r] - mnew);
        sv[sub][r] = p;
        psum += p;
      }
    }

    #pragma unroll
    for (int sub = 0; sub < 4; ++sub) {
      fp16x2 p01 = __builtin_amdgcn_cvt_pkrtz(sv[sub][0], sv[sub][1]);
      fp16x2 p23 = __builtin_amdgcn_cvt_pkrtz(sv[sub][2], sv[sub][3]);
      half4 pv;
      pv[0] = (_Float16)p01[0]; pv[1] = (_Float16)p01[1];
      pv[2] = (_Float16)p23[0]; pv[3] = (_Float16)p23[1];
      *(half4*)&Ps[wid * 16 + l16][sub * 16 + q4 * 4] = pv;
    }

    psum += __shfl_xor(psum, 16);
    psum += __shfl_xor(psum, 32);

    if (__any(mnew > m_r)) {
      const float alpha = exp2f(m_r - mnew);
      l_r = l_r * alpha + psum;
      m_r = mnew;
      #pragma unroll
      for (int sub = 0; sub < 4; ++sub)
        #pragma unroll
        for (int r = 0; r < 4; ++r) o[sub][r] *= alpha;
    } else {
      l_r += psum;
    }

    asm volatile("s_waitcnt lgkmcnt(0)" ::: "memory");

    const half8 pb0 = *(const half8*)&Ps[wid * 16 + l16][q4 * 8];
    const half8 pb1 = *(const half8*)&Ps[wid * 16 + l16][q4 * 8 + 32];
    #pragma unroll
    for (int sub = 0; sub < 4; ++sub) {
      const half8 va0 = *(const half8*)&Vs[sub * 16 + l16][q4 * 8];
      const half8 va1 = *(const half8*)&Vs[sub * 16 + l16][q4 * 8 + 32];
      o[sub] = mfma16(va0, pb0, o[sub]);
      o[sub] = mfma16(va1, pb1, o[sub]);
    }
  }

  const float inv = 1.0f / l_r;
  const int s = qt * 128 + wid * 16 + l16;
  #pragma unroll
  for (int sub = 0; sub < 4; ++sub) {
    half4 ov;
    #pragma unroll
    for (int r = 0; r < 4; ++r) ov[r] = (_Float16)(o[sub][r] * inv);
    *(half4*)(agg + (b * SS + s) * (HH * DHH) + h * DHH + sub * 16 + q4 * 4) = ov;
  }
}

// ---------------------------------------------------------------------------
// Kernel 3: output projection.  out[4096,1024] = agg @ Wot^T, single f16.
// Same DMA staging as qkv (2 arrays; half-array per wave).
// ---------------------------------------------------------------------------
__global__ __launch_bounds__(256) void out_gemm_kernel(
    const _Float16* __restrict__ agg, const _Float16* __restrict__ Wot,
    float* __restrict__ out)
{
  __shared__ alignas(16) _Float16 sA[128 * 32];
  __shared__ alignas(16) _Float16 sB[128 * 32];
  const int n0 = blockIdx.x * 128;   // 0..7
  const int m0 = blockIdx.y * 128;   // 0..31
  const int t = (int)threadIdx.x;
  const int lane = t & 63, wid = t >> 6;
  const int l16 = lane & 15, q4 = lane >> 4;
  const int mw = (wid & 1) * 64, nw = (wid >> 1) * 64;

  const int g  = (lane & 7) ^ ((lane >> 3) & 7);
  const int grow  = (lane >> 3) * 2 + (g >> 2);
  const int gcol8 = (g & 3) * 8;
  const int laneoff = (l16 >> 1) * 128 + (((((l16 & 1) << 2) | q4) ^ (l16 >> 1)) * 16);

  // wave 0: sA rows 0-63, wave 1: sA rows 64-127, waves 2,3: sB halves
  const _Float16* src = (wid < 2) ? (agg + m0 * 1024) : (Wot + n0 * 1024);
  _Float16* dst = (wid < 2) ? sA : sB;
  const int half64 = (wid & 1) * 64;
  const _Float16* gsrc = src + (half64 + grow) * 1024 + gcol8;
  _Float16* ldst = dst + half64 * 32;

  const floatx4 z4 = {0.0f, 0.0f, 0.0f, 0.0f};
  floatx4 acc[4][4];
  #pragma unroll
  for (int mi = 0; mi < 4; ++mi)
    #pragma unroll
    for (int ni = 0; ni < 4; ++ni) acc[mi][ni] = z4;

  for (int kt = 0; kt < 32; ++kt) {
    __syncthreads();
    {
      const _Float16* gp = gsrc + kt * 32;
      #pragma unroll
      for (int j = 0; j < 4; ++j)
        dma16(gp + j * 16 * 1024, ldst + j * 16 * 32);
    }
    __syncthreads();

    half8 a_f[4];
    #pragma unroll
    for (int mi = 0; mi < 4; ++mi)
      a_f[mi] = *(const half8*)((const char*)sA + (mw + mi * 16) * 64 + laneoff);
    #pragma unroll
    for (int ni = 0; ni < 4; ++ni) {
      const half8 b_f = *(const half8*)((const char*)sB + (nw + ni * 16) * 64 + laneoff);
      #pragma unroll
      for (int mi = 0; mi < 4; ++mi)
        acc[mi][ni] = mfma16(a_f[mi], b_f, acc[mi][ni]);
    }
  }

  #pragma unroll
  for (int ni = 0; ni < 4; ++ni)
    #pragma unroll
    for (int mi = 0; mi < 4; ++mi)
      #pragma unroll
      for (int r = 0; r < 4; ++r)
        out[(m0 + mw + mi * 16 + q4 * 4 + r) * 1024 + n0 + nw + ni * 16 + l16] =
            acc[mi][ni][r];
}

// ---------------------------------------------------------------------------
extern "C" void kernel_launch(void* const* d_in, const int* in_sizes, int n_in,
                              void* d_out, int out_size, void* d_ws, size_t ws_size,
                              hipStream_t stream)
{
  const float* tokens = (const float*)d_in[0];
  const float* wq = (const float*)d_in[1];
  const float* wk = (const float*)d_in[2];
  const float* wv = (const float*)d_in[3];
  const float* wo = (const float*)d_in[4];
  float* out = (float*)d_out;

  char* ws = (char*)d_ws;
  // layout (bytes):
  //   qh 0          ql 8388608    kh 16777216   kl 25165824   vt 33554432
  //   Wh 41943040 (6291456)   Wl 48234496 (6291456)   Wot 54525952 (2097152)
  //   th 56623104 (8388608)   tl 65011712 (8388608)      total 73400320
  //   agg aliases th (th dead after qkv_gemm)
  _Float16* qh  = (_Float16*)(ws);
  _Float16* ql  = (_Float16*)(ws + 8388608);
  _Float16* kh  = (_Float16*)(ws + 16777216);
  _Float16* kl  = (_Float16*)(ws + 25165824);
  _Float16* vt  = (_Float16*)(ws + 33554432);
  _Float16* Wh  = (_Float16*)(ws + 41943040);
  _Float16* Wl  = (_Float16*)(ws + 48234496);
  _Float16* Wot = (_Float16*)(ws + 54525952);
  _Float16* th  = (_Float16*)(ws + 56623104);
  _Float16* tl  = (_Float16*)(ws + 65011712);
  _Float16* agg = (_Float16*)(ws + 56623104);

  convert_kernel<<<dim3(16, 16, 4), 256, 0, stream>>>(wq, wk, wv, wo, Wh, Wl, Wot);
  tokens_split_kernel<<<2048, 256, 0, stream>>>(tokens, th, tl);
  qkv_gemm_kernel<<<dim3(24, 32), 256, 0, stream>>>(th, tl, Wh, Wl, qh, ql, kh, kl, vt);
  attn_kernel<<<dim3(16, 16, 2), 512, 0, stream>>>(qh, ql, kh, kl, vt, agg);
  out_gemm_kernel<<<dim3(8, 32), 256, 0, stream>>>(agg, Wot, out);
}

// Round 9
// 272.497 us; speedup vs baseline: 1.1147x; 1.1147x over previous
//
#include <hip/hip_runtime.h>
#include <hip/hip_fp16.h>
#include <stdint.h>

// Problem constants
#define BB 2
#define HH 16
#define SS 2048
#define DD 1024
#define DHH 64
// SCALE * log2(e): logits computed directly in log2 domain
#define QSCALE 0.18033688011112042f

typedef _Float16 half8 __attribute__((ext_vector_type(8)));
typedef _Float16 half4 __attribute__((ext_vector_type(4)));
typedef __fp16 fp16x2 __attribute__((ext_vector_type(2)));
typedef float floatx4 __attribute__((ext_vector_type(4)));

__device__ __forceinline__ floatx4 mfma16(half8 a, half8 b, floatx4 c) {
  return __builtin_amdgcn_mfma_f32_16x16x32_f16(a, b, c, 0, 0, 0);
}

// Async global->LDS DMA, 16B per lane (1KB per wave-issue).
__device__ __forceinline__ void dma16(const _Float16* g, _Float16* l) {
  __builtin_amdgcn_global_load_lds(
      (const __attribute__((address_space(1))) uint32_t*)g,
      (__attribute__((address_space(3))) uint32_t*)l,
      16, 0, 0);
}

// DMA-staged [128 rows][32 cols f16] tiles use an XOR swizzle within each
// 128B row-pair (8 chunks of 16B): global (row, chunk c) -> LDS chunk
// ((row&1)*4+c) ^ ((row>>1)&7).  Read side lands 2 lanes/chunk-group =
// conflict-free (verified R8: SQ_LDS_BANK_CONFLICT = 0).

// ---------------------------------------------------------------------------
// Kernel 0a: weight conversion (once per call).
// ---------------------------------------------------------------------------
__global__ __launch_bounds__(256) void convert_kernel(
    const float* __restrict__ wq, const float* __restrict__ wk,
    const float* __restrict__ wv, const float* __restrict__ wo,
    _Float16* __restrict__ Wh, _Float16* __restrict__ Wl,
    _Float16* __restrict__ Wot)
{
  __shared__ float St[64][68];
  const int kt = blockIdx.x;
  const int hy = blockIdx.y;
  const int z  = blockIdx.z;
  const int t  = (int)threadIdx.x;
  const int k0 = kt * 64;

  const float* src = (z == 0) ? (wq + hy * (DD * DHH))
                   : (z == 1) ? (wk + hy * (DD * DHH))
                   : (z == 2) ? (wv + hy * (DD * DHH))
                   : wo;

  const int rr = t >> 4, cc = (t & 15) * 4;
  if (z < 3) {
    #pragma unroll
    for (int i = 0; i < 4; ++i)
      *(floatx4*)&St[rr + 16 * i][cc] =
          *(const floatx4*)(src + (k0 + rr + 16 * i) * DHH + cc);
  } else {
    const int d0 = hy * 64;
    #pragma unroll
    for (int i = 0; i < 4; ++i)
      *(floatx4*)&St[rr + 16 * i][cc] =
          *(const floatx4*)(src + (k0 + rr + 16 * i) * 1024 + d0 + cc);
  }
  __syncthreads();

  const int e = t >> 2, kc = (t & 3) * 16;
  if (z < 3) {
    const int n = z * 1024 + hy * 64 + e;
    half8 hi0, hi1, lo0, lo1;
    #pragma unroll
    for (int u = 0; u < 16; ++u) {
      float x = St[kc + u][e];
      _Float16 hh = (_Float16)x;
      _Float16 ll = (_Float16)(x - (float)hh);
      if (u < 8) { hi0[u] = hh; lo0[u] = ll; }
      else       { hi1[u - 8] = hh; lo1[u - 8] = ll; }
    }
    *(half8*)(Wh + n * 1024 + k0 + kc)     = hi0;
    *(half8*)(Wh + n * 1024 + k0 + kc + 8) = hi1;
    *(half8*)(Wl + n * 1024 + k0 + kc)     = lo0;
    *(half8*)(Wl + n * 1024 + k0 + kc + 8) = lo1;
  } else {
    const int d0 = hy * 64;
    half8 hi0, hi1;
    #pragma unroll
    for (int u = 0; u < 16; ++u) {
      _Float16 hh = (_Float16)St[kc + u][e];
      if (u < 8) hi0[u] = hh; else hi1[u - 8] = hh;
    }
    *(half8*)(Wot + (d0 + e) * 1024 + k0 + kc)     = hi0;
    *(half8*)(Wot + (d0 + e) * 1024 + k0 + kc + 8) = hi1;
  }
}

// ---------------------------------------------------------------------------
// Kernel 0b: token split (elementwise, memory-bound).
// ---------------------------------------------------------------------------
__global__ __launch_bounds__(256) void tokens_split_kernel(
    const float* __restrict__ tokens,
    _Float16* __restrict__ th, _Float16* __restrict__ tl)
{
  const int i = ((int)blockIdx.x * 256 + (int)threadIdx.x) * 8;
  floatx4 x0 = *(const floatx4*)(tokens + i);
  floatx4 x1 = *(const floatx4*)(tokens + i + 4);
  half8 h, l;
  #pragma unroll
  for (int j = 0; j < 8; ++j) {
    float x = (j < 4) ? x0[j] : x1[j - 4];
    _Float16 hh = (_Float16)x;
    h[j] = hh;
    l[j] = (_Float16)(x - (float)hh);
  }
  *(half8*)(th + i) = h;
  *(half8*)(tl + i) = l;
}

// ---------------------------------------------------------------------------
// Kernel 1: fused QKV GEMM.  C[4096 m][3072 n], 128x128 tiles.
// DMA staging (one array per wave) + LDS DOUBLE BUFFER, one barrier per
// tile: DMA for kt+1 issues BEFORE computing kt, so the end-of-iter
// vmcnt(0) drain lands after ~48 MFMA of cover.  kt unrolled x2 so buffer
// indices are compile-time (avoids alias-forced vmcnt before ds_read).
// ---------------------------------------------------------------------------
__global__ __launch_bounds__(256) void qkv_gemm_kernel(
    const _Float16* __restrict__ th, const _Float16* __restrict__ tl,
    const _Float16* __restrict__ Wh, const _Float16* __restrict__ Wl,
    _Float16* __restrict__ qh, _Float16* __restrict__ ql,
    _Float16* __restrict__ kh, _Float16* __restrict__ kl,
    _Float16* __restrict__ vt)
{
  __shared__ alignas(16) _Float16 sbuf[2][4][128 * 32];   // 64 KB

  const int n0 = blockIdx.x * 128;   // 0..23
  const int m0 = blockIdx.y * 128;   // 0..31
  const int zb = n0 >> 10;           // 0=q, 1=k, 2=v
  const bool is_v = (zb == 2);
  const int t = (int)threadIdx.x;
  const int lane = t & 63, wid = t >> 6;
  const int l16 = lane & 15, q4 = lane >> 4;
  const int mw = (wid & 1) * 64, nw = (wid >> 1) * 64;

  // DMA lane mapping (per 16-row issue)
  const int g  = (lane & 7) ^ ((lane >> 3) & 7);
  const int grow  = (lane >> 3) * 2 + (g >> 2);
  const int gcol8 = (g & 3) * 8;
  // fragment-read lane offset (bytes within one 8KB array)
  const int laneoff = (l16 >> 1) * 128 + (((((l16 & 1) << 2) | q4) ^ (l16 >> 1)) * 16);

  // wave -> staged array: 0=Ah(th) 1=Bh(Wh) 2=Bl(Wl) 3=Al(tl)
  const _Float16* src;
  int arr;
  if (wid == 0)      { src = th + m0 * 1024; arr = 0; }
  else if (wid == 1) { src = Wh + n0 * 1024; arr = 1; }
  else if (wid == 2) { src = Wl + n0 * 1024; arr = 2; }
  else               { src = tl + m0 * 1024; arr = 3; }
  const bool stage_active = !(is_v && wid == 3);
  const _Float16* gsrc = src + grow * 1024 + gcol8;

  const floatx4 z4 = {0.0f, 0.0f, 0.0f, 0.0f};
  floatx4 acc[4][4];
  #pragma unroll
  for (int mi = 0; mi < 4; ++mi)
    #pragma unroll
    for (int ni = 0; ni < 4; ++ni) acc[mi][ni] = z4;

  auto stage = [&](int buf, int kt2) {
    if (stage_active) {
      const _Float16* gp = gsrc + kt2 * 32;
      _Float16* dst = &sbuf[buf][arr][0];
      #pragma unroll
      for (int j = 0; j < 8; ++j)
        dma16(gp + j * 16 * 1024, dst + j * 16 * 32);
    }
  };

  auto compute = [&](int buf) {
    const char* sAh = (const char*)&sbuf[buf][0][0];
    const char* sBh = (const char*)&sbuf[buf][1][0];
    const char* sBl = (const char*)&sbuf[buf][2][0];
    const char* sAl = (const char*)&sbuf[buf][3][0];
    half8 a_h[4];
    #pragma unroll
    for (int mi = 0; mi < 4; ++mi)
      a_h[mi] = *(const half8*)(sAh + (mw + mi * 16) * 64 + laneoff);
    if (!is_v) {
      half8 a_l[4];
      #pragma unroll
      for (int mi = 0; mi < 4; ++mi)
        a_l[mi] = *(const half8*)(sAl + (mw + mi * 16) * 64 + laneoff);
      #pragma unroll
      for (int ni = 0; ni < 4; ++ni) {
        const half8 b_h = *(const half8*)(sBh + (nw + ni * 16) * 64 + laneoff);
        const half8 b_l = *(const half8*)(sBl + (nw + ni * 16) * 64 + laneoff);
        #pragma unroll
        for (int mi = 0; mi < 4; ++mi) {
          acc[mi][ni] = mfma16(a_h[mi], b_h, acc[mi][ni]);
          acc[mi][ni] = mfma16(a_h[mi], b_l, acc[mi][ni]);
          acc[mi][ni] = mfma16(a_l[mi], b_h, acc[mi][ni]);
        }
      }
    } else {
      #pragma unroll
      for (int ni = 0; ni < 4; ++ni) {
        const half8 b_h = *(const half8*)(sBh + (nw + ni * 16) * 64 + laneoff);
        const half8 b_l = *(const half8*)(sBl + (nw + ni * 16) * 64 + laneoff);
        #pragma unroll
        for (int mi = 0; mi < 4; ++mi) {
          acc[mi][ni] = mfma16(a_h[mi], b_h, acc[mi][ni]);
          acc[mi][ni] = mfma16(a_h[mi], b_l, acc[mi][ni]);
        }
      }
    }
  };

  stage(0, 0);
  __syncthreads();                 // drain DMA for tile 0

  #pragma unroll 1
  for (int kt = 0; kt < 32; kt += 2) {
    if (kt + 1 < 32) stage(1, kt + 1);   // in flight under compute(0)
    compute(0);
    __syncthreads();                     // drain buf1 DMA + buf0 reads done
    if (kt + 2 < 32) stage(0, kt + 2);
    compute(1);
    __syncthreads();
  }

  // epilogue: C row=(q4*4+r within 16-tile), col=l16; zb uniform
  #pragma unroll
  for (int ni = 0; ni < 4; ++ni) {
    const int ncol = n0 + nw + ni * 16;
    const int h = (ncol >> 6) & 15;
    const int e = (ncol & 63) + l16;
    #pragma unroll
    for (int mi = 0; mi < 4; ++mi) {
      #pragma unroll
      for (int r = 0; r < 4; ++r) {
        const int grow2 = m0 + mw + mi * 16 + q4 * 4 + r;
        const int b = grow2 >> 11, s = grow2 & 2047;
        const float v = acc[mi][ni][r];
        const int qkidx = ((b * HH + h) * SS + s) * DHH + e;
        if (zb == 0) {
          const float vs = v * QSCALE;
          const _Float16 hh = (_Float16)vs;
          qh[qkidx] = hh;
          ql[qkidx] = (_Float16)(vs - (float)hh);
        } else if (zb == 1) {
          const _Float16 hh = (_Float16)v;
          kh[qkidx] = hh;
          kl[qkidx] = (_Float16)(v - (float)hh);
        } else {
          vt[((b * HH + h) * DHH + e) * SS + s] = (_Float16)v;
        }
      }
    }
  }
}

// ---------------------------------------------------------------------------
// Kernel 2: flash attention (unchanged from R7/R8 — register prefetch).
// ---------------------------------------------------------------------------
__global__ __launch_bounds__(512) void attn_kernel(
    const _Float16* __restrict__ qh, const _Float16* __restrict__ ql,
    const _Float16* __restrict__ kh, const _Float16* __restrict__ kl,
    const _Float16* __restrict__ vt, _Float16* __restrict__ agg)
{
  __shared__ _Float16 Kh[64][72], Kl[64][72], Vs[64][72];
  __shared__ _Float16 Ps[128][72];

  const int qt = blockIdx.x;
  const int h  = blockIdx.y;
  const int b  = blockIdx.z;
  const int bh = b * HH + h;
  const int t = (int)threadIdx.x;
  const int lane = t & 63, wid = t >> 6;
  const int l16 = lane & 15, q4 = lane >> 4;

  const int sr = t >> 3, sc = (t & 7) * 8;

  half8 qfh[2], qfl[2];
  {
    const int s = qt * 128 + wid * 16 + l16;
    const int base = (bh * SS + s) * DHH + q4 * 8;
    qfh[0] = *(const half8*)(qh + base);
    qfh[1] = *(const half8*)(qh + base + 32);
    qfl[0] = *(const half8*)(ql + base);
    qfl[1] = *(const half8*)(ql + base + 32);
  }

  const floatx4 z4 = {0.0f, 0.0f, 0.0f, 0.0f};
  floatx4 o[4];
  #pragma unroll
  for (int i = 0; i < 4; ++i) o[i] = z4;
  float m_r = -1e30f, l_r = 0.0f;

  half8 pK, pL, pV;
  {
    const int gk = (bh * SS + sr) * DHH + sc;
    pK = *(const half8*)(kh + gk);
    pL = *(const half8*)(kl + gk);
    pV = *(const half8*)(vt + (bh * DHH + sr) * SS + sc);
  }

  for (int kt = 0; kt < 32; ++kt) {
    __syncthreads();
    *(half8*)&Kh[sr][sc] = pK;
    *(half8*)&Kl[sr][sc] = pL;
    *(half8*)&Vs[sr][sc] = pV;
    __syncthreads();

    if (kt < 31) {
      const int k1 = (kt + 1) * 64;
      const int gk = (bh * SS + k1 + sr) * DHH + sc;
      pK = *(const half8*)(kh + gk);
      pL = *(const half8*)(kl + gk);
      pV = *(const half8*)(vt + (bh * DHH + sr) * SS + k1 + sc);
    }

    floatx4 sv[4];
    #pragma unroll
    for (int sub = 0; sub < 4; ++sub) {
      const half8 ah0 = *(const half8*)&Kh[sub * 16 + l16][q4 * 8];
      const half8 ah1 = *(const half8*)&Kh[sub * 16 + l16][q4 * 8 + 32];
      const half8 al0 = *(const half8*)&Kl[sub * 16 + l16][q4 * 8];
      const half8 al1 = *(const half8*)&Kl[sub * 16 + l16][q4 * 8 + 32];
      floatx4 s4 = z4;
      s4 = mfma16(ah0, qfh[0], s4);
      s4 = mfma16(ah1, qfh[1], s4);
      s4 = mfma16(al0, qfh[0], s4);
      s4 = mfma16(al1, qfh[1], s4);
      s4 = mfma16(ah0, qfl[0], s4);
      s4 = mfma16(ah1, qfl[1], s4);
      sv[sub] = s4;
    }

    float mx = fmaxf(fmaxf(sv[0][0], sv[0][1]), fmaxf(sv[0][2], sv[0][3]));
    #pragma unroll
    for (int sub = 1; sub < 4; ++sub)
      mx = fmaxf(mx, fmaxf(fmaxf(sv[sub][0], sv[sub][1]),
                           fmaxf(sv[sub][2], sv[sub][3])));
    mx = fmaxf(mx, __shfl_xor(mx, 16));
    mx = fmaxf(mx, __shfl_xor(mx, 32));
    const float mnew = fmaxf(m_r, mx);

    float psum = 0.0f;
    #pragma unroll
    for (int sub = 0; sub < 4; ++sub) {
      #pragma unroll
      for (int r = 0; r < 4; ++r) {
        float p = exp2f(sv[sub][r] - mnew);
        sv[sub][r] = p;
        psum += p;
      }
    }

    #pragma unroll
    for (int sub = 0; sub < 4; ++sub) {
      fp16x2 p01 = __builtin_amdgcn_cvt_pkrtz(sv[sub][0], sv[sub][1]);
      fp16x2 p23 = __builtin_amdgcn_cvt_pkrtz(sv[sub][2], sv[sub][3]);
      half4 pv;
      pv[0] = (_Float16)p01[0]; pv[1] = (_Float16)p01[1];
      pv[2] = (_Float16)p23[0]; pv[3] = (_Float16)p23[1];
      *(half4*)&Ps[wid * 16 + l16][sub * 16 + q4 * 4] = pv;
    }

    psum += __shfl_xor(psum, 16);
    psum += __shfl_xor(psum, 32);

    if (__any(mnew > m_r)) {
      const float alpha = exp2f(m_r - mnew);
      l_r = l_r * alpha + psum;
      m_r = mnew;
      #pragma unroll
      for (int sub = 0; sub < 4; ++sub)
        #pragma unroll
        for (int r = 0; r < 4; ++r) o[sub][r] *= alpha;
    } else {
      l_r += psum;
    }

    asm volatile("s_waitcnt lgkmcnt(0)" ::: "memory");

    const half8 pb0 = *(const half8*)&Ps[wid * 16 + l16][q4 * 8];
    const half8 pb1 = *(const half8*)&Ps[wid * 16 + l16][q4 * 8 + 32];
    #pragma unroll
    for (int sub = 0; sub < 4; ++sub) {
      const half8 va0 = *(const half8*)&Vs[sub * 16 + l16][q4 * 8];
      const half8 va1 = *(const half8*)&Vs[sub * 16 + l16][q4 * 8 + 32];
      o[sub] = mfma16(va0, pb0, o[sub]);
      o[sub] = mfma16(va1, pb1, o[sub]);
    }
  }

  const float inv = 1.0f / l_r;
  const int s = qt * 128 + wid * 16 + l16;
  #pragma unroll
  for (int sub = 0; sub < 4; ++sub) {
    half4 ov;
    #pragma unroll
    for (int r = 0; r < 4; ++r) ov[r] = (_Float16)(o[sub][r] * inv);
    *(half4*)(agg + (b * SS + s) * (HH * DHH) + h * DHH + sub * 16 + q4 * 4) = ov;
  }
}

// ---------------------------------------------------------------------------
// Kernel 3: output projection.  DMA staging + LDS double buffer (32 KB).
// ---------------------------------------------------------------------------
__global__ __launch_bounds__(256) void out_gemm_kernel(
    const _Float16* __restrict__ agg, const _Float16* __restrict__ Wot,
    float* __restrict__ out)
{
  __shared__ alignas(16) _Float16 sbuf[2][2][128 * 32];   // 32 KB
  const int n0 = blockIdx.x * 128;
  const int m0 = blockIdx.y * 128;
  const int t = (int)threadIdx.x;
  const int lane = t & 63, wid = t >> 6;
  const int l16 = lane & 15, q4 = lane >> 4;
  const int mw = (wid & 1) * 64, nw = (wid >> 1) * 64;

  const int g  = (lane & 7) ^ ((lane >> 3) & 7);
  const int grow  = (lane >> 3) * 2 + (g >> 2);
  const int gcol8 = (g & 3) * 8;
  const int laneoff = (l16 >> 1) * 128 + (((((l16 & 1) << 2) | q4) ^ (l16 >> 1)) * 16);

  const int arr = wid >> 1;              // 0: A (agg), 1: B (Wot)
  const int half64 = (wid & 1) * 64;
  const _Float16* src = (arr == 0) ? (agg + m0 * 1024) : (Wot + n0 * 1024);
  const _Float16* gsrc = src + (half64 + grow) * 1024 + gcol8;

  const floatx4 z4 = {0.0f, 0.0f, 0.0f, 0.0f};
  floatx4 acc[4][4];
  #pragma unroll
  for (int mi = 0; mi < 4; ++mi)
    #pragma unroll
    for (int ni = 0; ni < 4; ++ni) acc[mi][ni] = z4;

  auto stage = [&](int buf, int kt2) {
    const _Float16* gp = gsrc + kt2 * 32;
    _Float16* dst = &sbuf[buf][arr][half64 * 32];
    #pragma unroll
    for (int j = 0; j < 4; ++j)
      dma16(gp + j * 16 * 1024, dst + j * 16 * 32);
  };

  auto compute = [&](int buf) {
    const char* sA = (const char*)&sbuf[buf][0][0];
    const char* sB = (const char*)&sbuf[buf][1][0];
    half8 a_f[4];
    #pragma unroll
    for (int mi = 0; mi < 4; ++mi)
      a_f[mi] = *(const half8*)(sA + (mw + mi * 16) * 64 + laneoff);
    #pragma unroll
    for (int ni = 0; ni < 4; ++ni) {
      const half8 b_f = *(const half8*)(sB + (nw + ni * 16) * 64 + laneoff);
      #pragma unroll
      for (int mi = 0; mi < 4; ++mi)
        acc[mi][ni] = mfma16(a_f[mi], b_f, acc[mi][ni]);
    }
  };

  stage(0, 0);
  __syncthreads();

  #pragma unroll 1
  for (int kt = 0; kt < 32; kt += 2) {
    if (kt + 1 < 32) stage(1, kt + 1);
    compute(0);
    __syncthreads();
    if (kt + 2 < 32) stage(0, kt + 2);
    compute(1);
    __syncthreads();
  }

  #pragma unroll
  for (int ni = 0; ni < 4; ++ni)
    #pragma unroll
    for (int mi = 0; mi < 4; ++mi)
      #pragma unroll
      for (int r = 0; r < 4; ++r)
        out[(m0 + mw + mi * 16 + q4 * 4 + r) * 1024 + n0 + nw + ni * 16 + l16] =
            acc[mi][ni][r];
}

// ---------------------------------------------------------------------------
extern "C" void kernel_launch(void* const* d_in, const int* in_sizes, int n_in,
                              void* d_out, int out_size, void* d_ws, size_t ws_size,
                              hipStream_t stream)
{
  const float* tokens = (const float*)d_in[0];
  const float* wq = (const float*)d_in[1];
  const float* wk = (const float*)d_in[2];
  const float* wv = (const float*)d_in[3];
  const float* wo = (const float*)d_in[4];
  float* out = (float*)d_out;

  char* ws = (char*)d_ws;
  // layout (bytes):
  //   qh 0          ql 8388608    kh 16777216   kl 25165824   vt 33554432
  //   Wh 41943040 (6291456)   Wl 48234496 (6291456)   Wot 54525952 (2097152)
  //   th 56623104 (8388608)   tl 65011712 (8388608)      total 73400320
  //   agg aliases th (th dead after qkv_gemm)
  _Float16* qh  = (_Float16*)(ws);
  _Float16* ql  = (_Float16*)(ws + 8388608);
  _Float16* kh  = (_Float16*)(ws + 16777216);
  _Float16* kl  = (_Float16*)(ws + 25165824);
  _Float16* vt  = (_Float16*)(ws + 33554432);
  _Float16* Wh  = (_Float16*)(ws + 41943040);
  _Float16* Wl  = (_Float16*)(ws + 48234496);
  _Float16* Wot = (_Float16*)(ws + 54525952);
  _Float16* th  = (_Float16*)(ws + 56623104);
  _Float16* tl  = (_Float16*)(ws + 65011712);
  _Float16* agg = (_Float16*)(ws + 56623104);

  convert_kernel<<<dim3(16, 16, 4), 256, 0, stream>>>(wq, wk, wv, wo, Wh, Wl, Wot);
  tokens_split_kernel<<<2048, 256, 0, stream>>>(tokens, th, tl);
  qkv_gemm_kernel<<<dim3(24, 32), 256, 0, stream>>>(th, tl, Wh, Wl, qh, ql, kh, kl, vt);
  attn_kernel<<<dim3(16, 16, 2), 512, 0, stream>>>(qh, ql, kh, kl, vt, agg);
  out_gemm_kernel<<<dim3(8, 32), 256, 0, stream>>>(agg, Wot, out);
}